// Round 1
// baseline (914.620 us; speedup 1.0000x reference)
//
#include <hip/hip_runtime.h>
#include <math.h>

// Problem constants (fixed by setup_inputs)
#define LL 1536
#define NA 14
#define TOPK 30
#define NRBF 16
// K dim of edge GEMM: 16 (pos) + 14*14*16 (rbf) = 3152
#define KDIM 3152
#define KC 64

// ---------------------------------------------------------------------------
// Kernel A: per-row distances + top-30 selection (jax.lax.top_k semantics:
// smallest D_adjust first, ties -> lower index). Also copies x passthrough.
// ---------------------------------------------------------------------------
__global__ __launch_bounds__(64) void topk_kernel(
    const float* __restrict__ x, const float* __restrict__ mask,
    float* __restrict__ out_idx, float* __restrict__ out_x)
{
    __shared__ float ca[LL * 3];
    __shared__ float msk[LL];
    __shared__ float dist[LL];

    const int i = blockIdx.x;
    const int lane = threadIdx.x;

    for (int t = lane; t < LL; t += 64) {
        msk[t] = mask[t];
        ca[t * 3 + 0] = x[t * 42 + 3];
        ca[t * 3 + 1] = x[t * 42 + 4];
        ca[t * 3 + 2] = x[t * 42 + 5];
    }
    __syncthreads();

    const float cix = ca[i * 3 + 0], ciy = ca[i * 3 + 1], ciz = ca[i * 3 + 2];
    const float mi = msk[i];

    // pass 1: D = m2 * sqrt(|dX|^2 + 1e-6), row max
    float lmax = 0.f;
    for (int j = lane; j < LL; j += 64) {
        float dx = ca[j * 3 + 0] - cix;
        float dy = ca[j * 3 + 1] - ciy;
        float dz = ca[j * 3 + 2] - ciz;
        float d = sqrtf(dx * dx + dy * dy + dz * dz + 1e-6f);
        float m2 = mi * msk[j];
        float D = m2 * d;
        dist[j] = D;
        lmax = fmaxf(lmax, D);
    }
    #pragma unroll
    for (int m = 1; m < 64; m <<= 1) lmax = fmaxf(lmax, __shfl_xor(lmax, m));

    // pass 2: D_adjust = D + (1-m2)*D_max   (each entry owned by lane j%64)
    for (int j = lane; j < LL; j += 64) {
        float m2 = mi * msk[j];
        dist[j] = dist[j] + (1.f - m2) * lmax;
    }

    // selection: 30x argmin over packed (valbits<<32)|idx keys
    for (int t = 0; t < TOPK; ++t) {
        unsigned long long best = ~0ull;
        for (int j = lane; j < LL; j += 64) {
            unsigned bits = __float_as_uint(dist[j]);  // dist >= 0 -> monotone bits
            unsigned long long key = ((unsigned long long)bits << 32) | (unsigned)j;
            best = key < best ? key : best;
        }
        #pragma unroll
        for (int m = 1; m < 64; m <<= 1) {
            unsigned long long o = __shfl_xor(best, m);
            best = o < best ? o : best;
        }
        int j = (int)(best & 0xffffffffu);
        if (lane == (j & 63)) dist[j] = __uint_as_float(0x7f800000u); // +inf: remove
        if (lane == 0) out_idx[i * TOPK + t] = (float)j;
    }

    // x passthrough for this residue
    for (int t = lane; t < 42; t += 64) out_x[i * 42 + t] = x[i * 42 + t];
}

// ---------------------------------------------------------------------------
// Kernel B: node features V = LN(concat(one_hot(S,21), feat) @ W_node)
// ---------------------------------------------------------------------------
__global__ __launch_bounds__(128) void node_kernel(
    const float* __restrict__ feat, const float* __restrict__ W_node,
    const float* __restrict__ gamma, const float* __restrict__ beta,
    const int* __restrict__ S, float* __restrict__ V)
{
    __shared__ float f[128];
    __shared__ float red[128];
    __shared__ float mv[2];

    const int i = blockIdx.x;
    const int n = threadIdx.x;

    f[n] = feat[i * 128 + n];
    __syncthreads();

    float acc = W_node[S[i] * 128 + n];  // one-hot picks row S[i]
    #pragma unroll 8
    for (int c = 0; c < 128; ++c) acc = fmaf(f[c], W_node[(21 + c) * 128 + n], acc);

    red[n] = acc; __syncthreads();
    for (int s = 64; s > 0; s >>= 1) { if (n < s) red[n] += red[n + s]; __syncthreads(); }
    if (n == 0) mv[0] = red[0] * (1.f / 128.f);
    __syncthreads();
    float mean = mv[0];
    float cd = acc - mean;
    red[n] = cd * cd; __syncthreads();
    for (int s = 64; s > 0; s >>= 1) { if (n < s) red[n] += red[n + s]; __syncthreads(); }
    if (n == 0) mv[1] = red[0] * (1.f / 128.f);
    __syncthreads();
    float var = mv[1];

    V[i * 128 + n] = cd / sqrtf(var + 1e-5f) * gamma[n] + beta[n];
}

// ---------------------------------------------------------------------------
// Kernel C: edge features. One block per residue i: 30 edges (pad to 32 rows).
// C[32 x 128] = A[32 x 3152] @ W_edge[3152 x 128], A built on the fly
// (E_pos cols 0..15, RBF cols 16..3151), then LayerNorm per edge row.
// ---------------------------------------------------------------------------
__global__ __launch_bounds__(256) void edge_kernel(
    const float* __restrict__ x, const float* __restrict__ mask,
    const float* __restrict__ a14m, const float* __restrict__ W_pos,
    const float* __restrict__ b_pos, const float* __restrict__ W_edge,
    const float* __restrict__ gamma, const float* __restrict__ beta,
    const int* __restrict__ R_idx, const int* __restrict__ chain,
    const float* __restrict__ idxf, float* __restrict__ E)
{
    __shared__ float xi[42];
    __shared__ float mi[NA];
    __shared__ int   jl[TOPK];
    __shared__ float xj[TOPK][42];
    __shared__ float mj[TOPK][NA];
    __shared__ float Dp[TOPK][196];
    __shared__ float epos[TOPK][16];
    __shared__ __align__(16) float At[KC][32];
    __shared__ __align__(16) float Bs[KC][128];

    const int i = blockIdx.x;
    const int tid = threadIdx.x;

    if (tid < TOPK) jl[tid] = (int)idxf[i * TOPK + tid];
    if (tid >= 32 && tid < 74) xi[tid - 32] = x[i * 42 + (tid - 32)];
    if (tid >= 96 && tid < 96 + NA) mi[tid - 96] = a14m[i * NA + (tid - 96)] * mask[i];
    __syncthreads();

    for (int t = tid; t < TOPK * 42; t += 256) {
        int k = t / 42, c = t % 42;
        xj[k][c] = x[jl[k] * 42 + c];
    }
    for (int t = tid; t < TOPK * NA; t += 256) {
        int k = t / NA, a = t % NA;
        int j = jl[k];
        mj[k][a] = a14m[j * NA + a] * mask[j];
    }
    for (int t = tid; t < TOPK * 16; t += 256) {
        int k = t >> 4, c = t & 15;
        int j = jl[k];
        int off = R_idx[i] - R_idx[j];
        int ec = (chain[i] == chain[j]) ? 1 : 0;
        int dc = off + 32; dc = dc < 0 ? 0 : (dc > 64 ? 64 : dc);
        int d = ec ? dc : 65;
        epos[k][c] = W_pos[d * 16 + c] + b_pos[c];
    }
    __syncthreads();

    for (int t = tid; t < TOPK * 196; t += 256) {
        int k = t / 196, p = t % 196;
        int a1 = p / NA, a2 = p % NA;
        float dx = xi[a1 * 3 + 0] - xj[k][a2 * 3 + 0];
        float dy = xi[a1 * 3 + 1] - xj[k][a2 * 3 + 1];
        float dz = xi[a1 * 3 + 2] - xj[k][a2 * 3 + 2];
        Dp[k][p] = sqrtf(dx * dx + dy * dy + dz * dz + 1e-6f);
    }
    __syncthreads();

    const int mg = tid >> 5;          // 0..7 -> rows m0..m0+3
    const int ng = tid & 31;          // 0..31 -> cols n0..n0+3
    const int m0 = mg * 4, n0 = ng * 4;

    float acc[4][4] = {};

    for (int c0 = 0; c0 < KDIM; c0 += KC) {
        // stage W_edge chunk (vectorized, zero-padded past KDIM)
        for (int t = tid; t < KC * 32; t += 256) {
            int c = c0 + (t >> 5);
            float4 v;
            if (c < KDIM) v = *(const float4*)&W_edge[c * 128 + ((t & 31) << 2)];
            else { v.x = v.y = v.z = v.w = 0.f; }
            ((float4*)Bs)[t] = v;
        }
        // build A^T chunk
        for (int t = tid; t < KC * 32; t += 256) {
            int kk = t >> 5, m = t & 31;
            int c = c0 + kk;
            float v = 0.f;
            if (m < TOPK && c < KDIM) {
                if (c < 16) {
                    v = epos[m][c];
                } else {
                    int cc = c - 16;
                    int p = cc >> 4, r = cc & 15;
                    int a1 = p / NA, a2 = p % NA;
                    float dd = Dp[m][p];
                    float tt = (dd - (float)r * (20.f / 15.f)) * 0.8f;
                    v = __expf(-tt * tt) * mi[a1] * mj[m][a2];
                }
            }
            At[kk][m] = v;
        }
        __syncthreads();

        #pragma unroll 8
        for (int kk = 0; kk < KC; ++kk) {
            float av[4], bv[4];
            *(float4*)av = *(const float4*)&At[kk][m0];
            *(float4*)bv = *(const float4*)&Bs[kk][n0];
            #pragma unroll
            for (int mm = 0; mm < 4; ++mm)
                #pragma unroll
                for (int nn = 0; nn < 4; ++nn)
                    acc[mm][nn] = fmaf(av[mm], bv[nn], acc[mm][nn]);
        }
        __syncthreads();
    }

    // LayerNorm per edge row + store
    float4 g4 = *(const float4*)&gamma[n0];
    float4 b4 = *(const float4*)&beta[n0];
    #pragma unroll
    for (int mm = 0; mm < 4; ++mm) {
        int r = m0 + mm;
        float s = acc[mm][0] + acc[mm][1] + acc[mm][2] + acc[mm][3];
        #pragma unroll
        for (int msk2 = 1; msk2 < 32; msk2 <<= 1) s += __shfl_xor(s, msk2);
        float mean = s * (1.f / 128.f);
        float c0_ = acc[mm][0] - mean, c1_ = acc[mm][1] - mean;
        float c2_ = acc[mm][2] - mean, c3_ = acc[mm][3] - mean;
        float q = c0_ * c0_ + c1_ * c1_ + c2_ * c2_ + c3_ * c3_;
        #pragma unroll
        for (int msk2 = 1; msk2 < 32; msk2 <<= 1) q += __shfl_xor(q, msk2);
        float inv = 1.f / sqrtf(q * (1.f / 128.f) + 1e-5f);
        if (r < TOPK) {
            float4 o;
            o.x = c0_ * inv * g4.x + b4.x;
            o.y = c1_ * inv * g4.y + b4.y;
            o.z = c2_ * inv * g4.z + b4.z;
            o.w = c3_ * inv * g4.w + b4.w;
            *(float4*)&E[((size_t)i * TOPK + r) * 128 + n0] = o;
        }
    }
}

// ---------------------------------------------------------------------------
extern "C" void kernel_launch(void* const* d_in, const int* in_sizes, int n_in,
                              void* d_out, int out_size, void* d_ws, size_t ws_size,
                              hipStream_t stream)
{
    const float* x       = (const float*)d_in[0];
    const float* mask    = (const float*)d_in[1];
    const float* a14m    = (const float*)d_in[2];
    const float* feat    = (const float*)d_in[3];
    const float* W_pos   = (const float*)d_in[4];
    const float* b_pos   = (const float*)d_in[5];
    const float* W_edge  = (const float*)d_in[6];
    const float* gamma_e = (const float*)d_in[7];
    const float* beta_e  = (const float*)d_in[8];
    const float* W_node  = (const float*)d_in[9];
    const float* gamma_n = (const float*)d_in[10];
    const float* beta_n  = (const float*)d_in[11];
    const int*   S       = (const int*)d_in[12];
    const int*   R_idx   = (const int*)d_in[13];
    const int*   chain   = (const int*)d_in[14];

    float* out     = (float*)d_out;
    float* V       = out;                                  // 1536*128
    float* E       = out + 196608;                         // 1536*30*128
    float* out_idx = out + 196608 + 5898240;               // 1536*30
    float* out_x   = out_idx + 46080;                      // 1536*14*3

    topk_kernel<<<LL, 64, 0, stream>>>(x, mask, out_idx, out_x);
    node_kernel<<<LL, 128, 0, stream>>>(feat, W_node, gamma_n, beta_n, S, V);
    edge_kernel<<<LL, 256, 0, stream>>>(x, mask, a14m, W_pos, b_pos, W_edge,
                                        gamma_e, beta_e, R_idx, chain, out_idx, E);
}

// Round 2
// 185.625 us; speedup vs baseline: 4.9272x; 4.9272x over previous
//
#include <hip/hip_runtime.h>
#include <hip/hip_bf16.h>
#include <math.h>

// Problem constants (fixed by setup_inputs)
#define LL 1536
#define NA 14
#define TOPK 30
#define NRBF 16
#define KDIM 3152          // 16 (pos) + 14*14*16 (rbf)
#define KPAD 3200          // padded K (multiple of 64)
#define NCHUNK 50          // KPAD / 64
#define MU_STEP (20.0f/15.0f)
#define INV_SIG 0.8f

typedef __attribute__((ext_vector_type(8))) short bf16x8;
typedef __attribute__((ext_vector_type(4))) float f32x4;

static __device__ __forceinline__ ushort f2bf(float f) {
    union { __hip_bfloat16 h; ushort u; } v;
    v.h = __float2bfloat16(f);
    return v.u;
}

// ---------------------------------------------------------------------------
// Kernel 0: W_edge [3152][128] f32  ->  Wt [128][3200] bf16 (transposed, padded)
// ---------------------------------------------------------------------------
__global__ __launch_bounds__(256) void convert_wedge(
    const float* __restrict__ W_edge, ushort* __restrict__ Wt)
{
    int t = blockIdx.x * 256 + threadIdx.x;
    if (t >= 128 * KPAD) return;
    int n = t / KPAD, k = t - n * KPAD;
    Wt[t] = (k < KDIM) ? f2bf(W_edge[k * 128 + n]) : (ushort)0;
}

// ---------------------------------------------------------------------------
// Kernel A: per-row distances + top-30 selection (lax.top_k tie-break: lower
// index first). Also copies x passthrough.
// ---------------------------------------------------------------------------
__global__ __launch_bounds__(64) void topk_kernel(
    const float* __restrict__ x, const float* __restrict__ mask,
    float* __restrict__ out_idx, float* __restrict__ out_x)
{
    __shared__ float ca[LL * 3];
    __shared__ float msk[LL];
    __shared__ float dist[LL];

    const int i = blockIdx.x;
    const int lane = threadIdx.x;

    for (int t = lane; t < LL; t += 64) {
        msk[t] = mask[t];
        ca[t * 3 + 0] = x[t * 42 + 3];
        ca[t * 3 + 1] = x[t * 42 + 4];
        ca[t * 3 + 2] = x[t * 42 + 5];
    }
    __syncthreads();

    const float cix = ca[i * 3 + 0], ciy = ca[i * 3 + 1], ciz = ca[i * 3 + 2];
    const float mi = msk[i];

    float lmax = 0.f;
    for (int j = lane; j < LL; j += 64) {
        float dx = ca[j * 3 + 0] - cix;
        float dy = ca[j * 3 + 1] - ciy;
        float dz = ca[j * 3 + 2] - ciz;
        float d = sqrtf(dx * dx + dy * dy + dz * dz + 1e-6f);
        float m2 = mi * msk[j];
        float D = m2 * d;
        dist[j] = D;
        lmax = fmaxf(lmax, D);
    }
    #pragma unroll
    for (int m = 1; m < 64; m <<= 1) lmax = fmaxf(lmax, __shfl_xor(lmax, m));

    for (int j = lane; j < LL; j += 64) {
        float m2 = mi * msk[j];
        dist[j] = dist[j] + (1.f - m2) * lmax;
    }

    for (int t = 0; t < TOPK; ++t) {
        unsigned long long best = ~0ull;
        for (int j = lane; j < LL; j += 64) {
            unsigned bits = __float_as_uint(dist[j]);
            unsigned long long key = ((unsigned long long)bits << 32) | (unsigned)j;
            best = key < best ? key : best;
        }
        #pragma unroll
        for (int m = 1; m < 64; m <<= 1) {
            unsigned long long o = __shfl_xor(best, m);
            best = o < best ? o : best;
        }
        int j = (int)(best & 0xffffffffu);
        if (lane == (j & 63)) dist[j] = __uint_as_float(0x7f800000u);
        if (lane == 0) out_idx[i * TOPK + t] = (float)j;
    }

    for (int t = lane; t < 42; t += 64) out_x[i * 42 + t] = x[i * 42 + t];
}

// ---------------------------------------------------------------------------
// Kernel B: node features V = LN(concat(one_hot(S,21), feat) @ W_node)
// ---------------------------------------------------------------------------
__global__ __launch_bounds__(128) void node_kernel(
    const float* __restrict__ feat, const float* __restrict__ W_node,
    const float* __restrict__ gamma, const float* __restrict__ beta,
    const int* __restrict__ S, float* __restrict__ V)
{
    __shared__ float f[128];
    __shared__ float red[128];
    __shared__ float mv[2];

    const int i = blockIdx.x;
    const int n = threadIdx.x;

    f[n] = feat[i * 128 + n];
    __syncthreads();

    float acc = W_node[S[i] * 128 + n];
    #pragma unroll 8
    for (int c = 0; c < 128; ++c) acc = fmaf(f[c], W_node[(21 + c) * 128 + n], acc);

    red[n] = acc; __syncthreads();
    for (int s = 64; s > 0; s >>= 1) { if (n < s) red[n] += red[n + s]; __syncthreads(); }
    if (n == 0) mv[0] = red[0] * (1.f / 128.f);
    __syncthreads();
    float mean = mv[0];
    float cd = acc - mean;
    red[n] = cd * cd; __syncthreads();
    for (int s = 64; s > 0; s >>= 1) { if (n < s) red[n] += red[n + s]; __syncthreads(); }
    if (n == 0) mv[1] = red[0] * (1.f / 128.f);
    __syncthreads();
    float var = mv[1];

    V[i * 128 + n] = cd / sqrtf(var + 1e-5f) * gamma[n] + beta[n];
}

// ---------------------------------------------------------------------------
// Kernel C (MFMA): per block 2 residues -> C[64 x 128] = A[64 x 3200] @ W[3200 x 128]
// A rows: row = g*32 + e (e<30 valid). A built on the fly into LDS bf16.
// B = Wt (pre-transposed bf16). mfma_f32_16x16x32_bf16, fp32 accum, LN epilogue.
// ---------------------------------------------------------------------------
__global__ __launch_bounds__(256) void edge_mfma_kernel(
    const float* __restrict__ x, const float* __restrict__ mask,
    const float* __restrict__ a14m, const float* __restrict__ W_pos,
    const float* __restrict__ b_pos, const ushort* __restrict__ Wt,
    const float* __restrict__ gamma, const float* __restrict__ beta,
    const int* __restrict__ R_idx, const int* __restrict__ chain,
    const float* __restrict__ idxf, float* __restrict__ E)
{
    __shared__ float xi2[2][44];
    __shared__ float mi2[2][16];
    __shared__ int   jl[64];
    __shared__ float xjs[64][44];
    __shared__ float mjs[64][14];
    __shared__ float eposs[64][16];
    __shared__ __align__(16) ushort As[64][72];
    __shared__ __align__(16) ushort Bs[128][72];
    __shared__ float lnS[64][2];
    __shared__ float lnQ[64][2];

    const int i0 = blockIdx.x * 2;
    const int tid = threadIdx.x;

    // ---- stage per-block metadata ----
    if (tid < 64) {
        int g = tid >> 5, e = tid & 31;
        jl[tid] = (e < TOPK) ? (int)idxf[(i0 + g) * TOPK + e] : 0;
    } else if (tid < 64 + 84) {
        int t = tid - 64; int g = t / 42, c = t - g * 42;
        xi2[g][c] = x[(i0 + g) * 42 + c];
    } else if (tid < 148 + 28) {
        int t = tid - 148; int g = t / 14, a = t - g * 14;
        mi2[g][a] = a14m[(i0 + g) * 14 + a] * mask[i0 + g];
    }
    __syncthreads();

    for (int t = tid; t < 64 * 42; t += 256) {
        int row = t / 42, c = t - row * 42;
        xjs[row][c] = x[jl[row] * 42 + c];
    }
    for (int t = tid; t < 64 * 14; t += 256) {
        int row = t / 14, a = t - row * 14;
        int e = row & 31, j = jl[row];
        mjs[row][a] = (e < TOPK) ? a14m[j * 14 + a] * mask[j] : 0.f;
    }
    for (int t = tid; t < 64 * 16; t += 256) {
        int row = t >> 4, c = t & 15;
        int e = row & 31, g = row >> 5;
        float v = 0.f;
        if (e < TOPK) {
            int i = i0 + g, j = jl[row];
            int off = R_idx[i] - R_idx[j];
            int ec = (chain[i] == chain[j]) ? 1 : 0;
            int dc = off + 32; dc = dc < 0 ? 0 : (dc > 64 ? 64 : dc);
            int d = ec ? dc : 65;
            v = W_pos[d * 16 + c] + b_pos[c];
        }
        eposs[row][c] = v;
    }
    __syncthreads();

    const int wave = tid >> 6, lane = tid & 63;
    const int l16 = lane & 15, lk = lane >> 4;
    const int mh = wave >> 1, nh = wave & 1;

    f32x4 acc[2][4] = {};

    for (int ch = 0; ch < NCHUNK; ++ch) {
        const int k0 = ch * 64;

        // stage B chunk: Bs[n][0..63] = Wt[n][k0..k0+63]
        #pragma unroll
        for (int it = 0; it < 4; ++it) {
            int item = tid + it * 256;          // 1024 items = 128 rows x 8 segs
            int n = item >> 3, seg = item & 7;
            uint4 v = *(const uint4*)&Wt[n * KPAD + k0 + seg * 8];
            *(uint4*)&Bs[n][seg * 8] = v;
        }

        // build A chunk: As[row][0..63] for c = k0..k0+63
        #pragma unroll
        for (int it = 0; it < 2; ++it) {
            int item = tid + it * 256;          // 512 items = 64 rows x 8 segs
            int row = item >> 3, seg = item & 7;
            int c0 = k0 + seg * 8;
            union { ushort u[8]; uint4 v; } o;
            if (c0 < 16) {                       // E_pos columns (chunk 0, segs 0-1)
                #pragma unroll
                for (int j = 0; j < 8; ++j) o.u[j] = f2bf(eposs[row][c0 + j]);
            } else {
                int cc = c0 - 16;
                int p = cc >> 4, r0 = cc & 15;   // r0 in {0,8}
                if (p < 196) {
                    int g = row >> 5;
                    int a1 = p / 14, a2 = p - a1 * 14;
                    float dx = xi2[g][a1 * 3 + 0] - xjs[row][a2 * 3 + 0];
                    float dy = xi2[g][a1 * 3 + 1] - xjs[row][a2 * 3 + 1];
                    float dz = xi2[g][a1 * 3 + 2] - xjs[row][a2 * 3 + 2];
                    float dd = sqrtf(dx * dx + dy * dy + dz * dz + 1e-6f);
                    float coef = mi2[g][a1] * mjs[row][a2];
                    #pragma unroll
                    for (int j = 0; j < 8; ++j) {
                        float tt = (dd - (float)(r0 + j) * MU_STEP) * INV_SIG;
                        o.u[j] = f2bf(__expf(-tt * tt) * coef);
                    }
                } else {
                    #pragma unroll
                    for (int j = 0; j < 8; ++j) o.u[j] = 0;
                }
            }
            *(uint4*)&As[row][seg * 8] = o.v;
        }
        __syncthreads();

        // MFMA: 2 K-steps of 32
        #pragma unroll
        for (int ks = 0; ks < 2; ++ks) {
            const int ko = ks * 32 + lk * 8;
            bf16x8 a0 = *(const bf16x8*)&As[mh * 32 + l16][ko];
            bf16x8 a1 = *(const bf16x8*)&As[mh * 32 + 16 + l16][ko];
            bf16x8 b0 = *(const bf16x8*)&Bs[nh * 64 + l16][ko];
            bf16x8 b1 = *(const bf16x8*)&Bs[nh * 64 + 16 + l16][ko];
            bf16x8 b2 = *(const bf16x8*)&Bs[nh * 64 + 32 + l16][ko];
            bf16x8 b3 = *(const bf16x8*)&Bs[nh * 64 + 48 + l16][ko];
            acc[0][0] = __builtin_amdgcn_mfma_f32_16x16x32_bf16(a0, b0, acc[0][0], 0, 0, 0);
            acc[0][1] = __builtin_amdgcn_mfma_f32_16x16x32_bf16(a0, b1, acc[0][1], 0, 0, 0);
            acc[0][2] = __builtin_amdgcn_mfma_f32_16x16x32_bf16(a0, b2, acc[0][2], 0, 0, 0);
            acc[0][3] = __builtin_amdgcn_mfma_f32_16x16x32_bf16(a0, b3, acc[0][3], 0, 0, 0);
            acc[1][0] = __builtin_amdgcn_mfma_f32_16x16x32_bf16(a1, b0, acc[1][0], 0, 0, 0);
            acc[1][1] = __builtin_amdgcn_mfma_f32_16x16x32_bf16(a1, b1, acc[1][1], 0, 0, 0);
            acc[1][2] = __builtin_amdgcn_mfma_f32_16x16x32_bf16(a1, b2, acc[1][2], 0, 0, 0);
            acc[1][3] = __builtin_amdgcn_mfma_f32_16x16x32_bf16(a1, b3, acc[1][3], 0, 0, 0);
        }
        __syncthreads();
    }

    // ---- LayerNorm epilogue ----
    // C/D layout: col = lane&15, row_in_frag = (lane>>4)*4 + reg  [m89]
    #pragma unroll
    for (int f = 0; f < 2; ++f) {
        #pragma unroll
        for (int reg = 0; reg < 4; ++reg) {
            float s = acc[f][0][reg] + acc[f][1][reg] + acc[f][2][reg] + acc[f][3][reg];
            float q = acc[f][0][reg] * acc[f][0][reg] + acc[f][1][reg] * acc[f][1][reg]
                    + acc[f][2][reg] * acc[f][2][reg] + acc[f][3][reg] * acc[f][3][reg];
            #pragma unroll
            for (int m = 1; m < 16; m <<= 1) {
                s += __shfl_xor(s, m);
                q += __shfl_xor(q, m);
            }
            if (l16 == 0) {
                int row = mh * 32 + f * 16 + lk * 4 + reg;
                lnS[row][nh] = s;
                lnQ[row][nh] = q;
            }
        }
    }
    __syncthreads();

    float gl[4], bl[4];
    #pragma unroll
    for (int nf = 0; nf < 4; ++nf) {
        int col = nh * 64 + nf * 16 + l16;
        gl[nf] = gamma[col];
        bl[nf] = beta[col];
    }
    #pragma unroll
    for (int f = 0; f < 2; ++f) {
        #pragma unroll
        for (int reg = 0; reg < 4; ++reg) {
            int r = mh * 32 + f * 16 + lk * 4 + reg;
            int e = r & 31, g = r >> 5;
            if (e < TOPK) {
                float s = lnS[r][0] + lnS[r][1];
                float q = lnQ[r][0] + lnQ[r][1];
                float mean = s * (1.f / 128.f);
                float var = q * (1.f / 128.f) - mean * mean;
                float inv = 1.f / sqrtf(var + 1e-5f);
                float* dst = &E[((size_t)((i0 + g) * TOPK + e)) * 128];
                #pragma unroll
                for (int nf = 0; nf < 4; ++nf) {
                    int col = nh * 64 + nf * 16 + l16;
                    dst[col] = (acc[f][nf][reg] - mean) * inv * gl[nf] + bl[nf];
                }
            }
        }
    }
}

// ---------------------------------------------------------------------------
extern "C" void kernel_launch(void* const* d_in, const int* in_sizes, int n_in,
                              void* d_out, int out_size, void* d_ws, size_t ws_size,
                              hipStream_t stream)
{
    const float* x       = (const float*)d_in[0];
    const float* mask    = (const float*)d_in[1];
    const float* a14m    = (const float*)d_in[2];
    const float* feat    = (const float*)d_in[3];
    const float* W_pos   = (const float*)d_in[4];
    const float* b_pos   = (const float*)d_in[5];
    const float* W_edge  = (const float*)d_in[6];
    const float* gamma_e = (const float*)d_in[7];
    const float* beta_e  = (const float*)d_in[8];
    const float* W_node  = (const float*)d_in[9];
    const float* gamma_n = (const float*)d_in[10];
    const float* beta_n  = (const float*)d_in[11];
    const int*   S       = (const int*)d_in[12];
    const int*   R_idx   = (const int*)d_in[13];
    const int*   chain   = (const int*)d_in[14];

    float* out     = (float*)d_out;
    float* V       = out;                                  // 1536*128
    float* E       = out + 196608;                         // 1536*30*128
    float* out_idx = out + 196608 + 5898240;               // 1536*30
    float* out_x   = out_idx + 46080;                      // 1536*14*3

    ushort* Wt = (ushort*)d_ws;                            // 128*3200 bf16 = 819200 B

    convert_wedge<<<(128 * KPAD + 255) / 256, 256, 0, stream>>>(W_edge, Wt);
    topk_kernel<<<LL, 64, 0, stream>>>(x, mask, out_idx, out_x);
    node_kernel<<<LL, 128, 0, stream>>>(feat, W_node, gamma_n, beta_n, S, V);
    edge_mfma_kernel<<<LL / 2, 256, 0, stream>>>(x, mask, a14m, W_pos, b_pos, Wt,
                                                 gamma_e, beta_e, R_idx, chain,
                                                 out_idx, E);
}

// Round 3
// 125.976 us; speedup vs baseline: 7.2603x; 1.4735x over previous
//
#include <hip/hip_runtime.h>
#include <hip/hip_bf16.h>
#include <math.h>

// Problem constants (fixed by setup_inputs)
#define LL 1536
#define NA 14
#define TOPK 30
#define NRBF 16
#define KDIM 3152          // 16 (pos) + 14*14*16 (rbf)
#define KPAD 3200          // padded K (multiple of 64)
#define NCHUNK 50          // KPAD / 64

typedef __attribute__((ext_vector_type(8))) short bf16x8;
typedef __attribute__((ext_vector_type(4))) float f32x4;

static __device__ __forceinline__ ushort f2bf(float f) {
    union { __hip_bfloat16 h; ushort u; } v;
    v.h = __float2bfloat16(f);
    return v.u;
}

#define ASYNC16(ldsp, gp)                                                     \
    __builtin_amdgcn_global_load_lds(                                         \
        (const __attribute__((address_space(1))) void*)(gp),                  \
        (__attribute__((address_space(3))) void*)(ldsp), 16, 0, 0)

// ---------------------------------------------------------------------------
// Kernel 0: W_edge [3152][128] f32 -> Wt [128][3200] bf16, tiled transpose.
// ---------------------------------------------------------------------------
__global__ __launch_bounds__(256) void convert_wedge(
    const float* __restrict__ W_edge, ushort* __restrict__ Wt)
{
    __shared__ float tile[64][65];
    const int k0 = blockIdx.x * 64, n0 = blockIdx.y * 64;
    const int t = threadIdx.x;
    #pragma unroll
    for (int r = 0; r < 16; ++r) {
        int idx = r * 256 + t;
        int kl = idx >> 6, nl = idx & 63;
        int k = k0 + kl;
        tile[nl][kl] = (k < KDIM) ? W_edge[k * 128 + n0 + nl] : 0.f;
    }
    __syncthreads();
    #pragma unroll
    for (int r = 0; r < 16; ++r) {
        int idx = r * 256 + t;
        int nl = idx >> 6, kl = idx & 63;
        Wt[(size_t)(n0 + nl) * KPAD + k0 + kl] = f2bf(tile[nl][kl]);
    }
}

// ---------------------------------------------------------------------------
// Kernel A: top-30 selection, register-resident candidates.
// ---------------------------------------------------------------------------
static __device__ __forceinline__ unsigned long long u64min(
    unsigned long long a, unsigned long long b) { return a < b ? a : b; }

__global__ __launch_bounds__(64) void topk_kernel(
    const float* __restrict__ x, const float* __restrict__ mask,
    float* __restrict__ out_idx, float* __restrict__ out_x)
{
    __shared__ float ca[LL * 3];
    __shared__ float msk[LL];

    const int i = blockIdx.x;
    const int lane = threadIdx.x;

    for (int t = lane; t < LL; t += 64) {
        msk[t] = mask[t];
        ca[t * 3 + 0] = x[t * 42 + 3];
        ca[t * 3 + 1] = x[t * 42 + 4];
        ca[t * 3 + 2] = x[t * 42 + 5];
    }
    __syncthreads();

    const float cix = ca[i * 3 + 0], ciy = ca[i * 3 + 1], ciz = ca[i * 3 + 2];
    const float mi = msk[i];

    float d[24], m2a[24];
    float lmax = 0.f;
    #pragma unroll
    for (int c = 0; c < 24; ++c) {
        int j = lane + c * 64;
        float dx = ca[j * 3 + 0] - cix;
        float dy = ca[j * 3 + 1] - ciy;
        float dz = ca[j * 3 + 2] - ciz;
        float m2 = mi * msk[j];
        float D = m2 * sqrtf(dx * dx + dy * dy + dz * dz + 1e-6f);
        d[c] = D; m2a[c] = m2;
        lmax = fmaxf(lmax, D);
    }
    #pragma unroll
    for (int m = 1; m < 64; m <<= 1) lmax = fmaxf(lmax, __shfl_xor(lmax, m));

    unsigned long long key[24];
    #pragma unroll
    for (int c = 0; c < 24; ++c) {
        float adj = d[c] + (1.f - m2a[c]) * lmax;    // D_adjust >= 0
        key[c] = ((unsigned long long)__float_as_uint(adj) << 32)
               | (unsigned)(lane + c * 64);
    }

    for (int t = 0; t < TOPK; ++t) {
        unsigned long long m12[12];
        #pragma unroll
        for (int c = 0; c < 12; ++c) m12[c] = u64min(key[2 * c], key[2 * c + 1]);
        #pragma unroll
        for (int c = 0; c < 6; ++c) m12[c] = u64min(m12[2 * c], m12[2 * c + 1]);
        unsigned long long best = u64min(u64min(m12[0], m12[1]),
                                         u64min(m12[2], u64min(m12[3], u64min(m12[4], m12[5]))));
        #pragma unroll
        for (int m = 1; m < 64; m <<= 1) best = u64min(best, __shfl_xor(best, m));
        if (lane == 0) out_idx[i * TOPK + t] = (float)(unsigned)(best & 0xffffffffu);
        #pragma unroll
        for (int c = 0; c < 24; ++c) if (key[c] == best) key[c] = ~0ull;
    }

    for (int t = lane; t < 42; t += 64) out_x[i * 42 + t] = x[i * 42 + t];
}

// ---------------------------------------------------------------------------
// Kernel B: node features V = LN(concat(one_hot(S,21), feat) @ W_node)
// ---------------------------------------------------------------------------
__global__ __launch_bounds__(128) void node_kernel(
    const float* __restrict__ feat, const float* __restrict__ W_node,
    const float* __restrict__ gamma, const float* __restrict__ beta,
    const int* __restrict__ S, float* __restrict__ V)
{
    __shared__ float f[128];
    __shared__ float red[128];
    __shared__ float mv[2];

    const int i = blockIdx.x;
    const int n = threadIdx.x;

    f[n] = feat[i * 128 + n];
    __syncthreads();

    float acc = W_node[S[i] * 128 + n];
    #pragma unroll 8
    for (int c = 0; c < 128; ++c) acc = fmaf(f[c], W_node[(21 + c) * 128 + n], acc);

    red[n] = acc; __syncthreads();
    for (int s = 64; s > 0; s >>= 1) { if (n < s) red[n] += red[n + s]; __syncthreads(); }
    if (n == 0) mv[0] = red[0] * (1.f / 128.f);
    __syncthreads();
    float mean = mv[0];
    float cd = acc - mean;
    red[n] = cd * cd; __syncthreads();
    for (int s = 64; s > 0; s >>= 1) { if (n < s) red[n] += red[n + s]; __syncthreads(); }
    if (n == 0) mv[1] = red[0] * (1.f / 128.f);
    __syncthreads();
    float var = mv[1];

    V[i * 128 + n] = cd / sqrtf(var + 1e-5f) * gamma[n] + beta[n];
}

// ---------------------------------------------------------------------------
// Kernel C (MFMA): per block 2 residues, C[64x128] = A[64x3200] @ Wt^T.
// A built on the fly: 1 thread per (row, atom-pair) per 64-col chunk, exp-chain
// recurrence (5 exps instead of 16 per distance). Bs staged via
// global_load_lds with pre-swizzled source; reads XOR-deswizzle.
// ---------------------------------------------------------------------------
__global__ __launch_bounds__(256) void edge_mfma_kernel(
    const float* __restrict__ x, const float* __restrict__ mask,
    const float* __restrict__ a14m, const float* __restrict__ W_pos,
    const float* __restrict__ b_pos, const ushort* __restrict__ Wt,
    const float* __restrict__ gamma, const float* __restrict__ beta,
    const int* __restrict__ R_idx, const int* __restrict__ chain,
    const float* __restrict__ idxf, float* __restrict__ E)
{
    __shared__ float xi2[2][44];
    __shared__ float mi2[2][16];
    __shared__ int   jl[64];
    __shared__ float xjs[64][44];
    __shared__ float mjs[64][14];
    __shared__ __align__(16) ushort eposs[64][16];
    __shared__ __align__(16) ushort As[64][72];     // stride 72 -> balanced b128
    __shared__ __align__(16) ushort Bs[128 * 64];   // linear, XOR-swizzled data
    __shared__ float lnS[64][2];
    __shared__ float lnQ[64][2];

    const int i0 = blockIdx.x * 2;
    const int tid = threadIdx.x;

    // ---- stage per-block metadata ----
    if (tid < 64) {
        int g = tid >> 5, e = tid & 31;
        jl[tid] = (e < TOPK) ? (int)idxf[(i0 + g) * TOPK + e] : 0;
    } else if (tid < 64 + 84) {
        int t = tid - 64; int g = t / 42, c = t - g * 42;
        xi2[g][c] = x[(i0 + g) * 42 + c];
    } else if (tid < 148 + 28) {
        int t = tid - 148; int g = t / 14, a = t - g * 14;
        mi2[g][a] = a14m[(i0 + g) * 14 + a] * mask[i0 + g];
    }
    __syncthreads();

    for (int t = tid; t < 64 * 42; t += 256) {
        int row = t / 42, c = t - row * 42;
        xjs[row][c] = x[jl[row] * 42 + c];
    }
    for (int t = tid; t < 64 * 14; t += 256) {
        int row = t / 14, a = t - row * 14;
        int e = row & 31, j = jl[row];
        mjs[row][a] = (e < TOPK) ? a14m[j * 14 + a] * mask[j] : 0.f;
    }
    for (int t = tid; t < 64 * 16; t += 256) {
        int row = t >> 4, c = t & 15;
        int e = row & 31, g = row >> 5;
        float v = 0.f;
        if (e < TOPK) {
            int i = i0 + g, j = jl[row];
            int off = R_idx[i] - R_idx[j];
            int ec = (chain[i] == chain[j]) ? 1 : 0;
            int dc = off + 32; dc = dc < 0 ? 0 : (dc > 64 ? 64 : dc);
            int d = ec ? dc : 65;
            v = W_pos[d * 16 + c] + b_pos[c];
        }
        eposs[row][c] = f2bf(v);
    }

    // chain constants: c_j = exp(-dv^2*(2j-1)), dv = 16/15 in sigma units
    float cj[16];
    #pragma unroll
    for (int j = 1; j < 16; ++j) cj[j] = __expf(-1.13777778f * (float)(2 * j - 1));
    __syncthreads();

    const int wave = tid >> 6, lane = tid & 63;
    const int l16 = lane & 15, lk = lane >> 4;
    const int mh = wave >> 1, nh = wave & 1;
    const int arow = tid >> 2, apl = tid & 3;   // A-build: 1 thread = 1 (row,pair)
    const int ag = arow >> 5;

    // Bs staging geometry: wave stages rows [wave*32, wave*32+32)
    const int sn0 = wave * 32 + (lane >> 3);
    const int skseg = (lane & 7) ^ (lane >> 3);     // pre-swizzled source slot
    const ushort* gsrc0 = Wt + (size_t)sn0 * KPAD + skseg * 8;
    ushort* lds0 = &Bs[wave * 2048];

    f32x4 acc[2][4] = {};

    for (int ch = 0; ch < NCHUNK; ++ch) {
        // 1. async-stage Bs chunk (16B/lane, wave-uniform LDS base)
        #pragma unroll
        for (int it = 0; it < 4; ++it) {
            ASYNC16(lds0 + it * 512, gsrc0 + (size_t)it * 8 * KPAD + ch * 64);
        }

        // 2. build A: this thread's (row, pair) for this chunk
        int p = 4 * ch + apl - 1;
        if (p < 0) {                                  // E_pos cols 0..15 (ch 0)
            *(uint4*)&As[arow][0] = *(const uint4*)&eposs[arow][0];
            *(uint4*)&As[arow][8] = *(const uint4*)&eposs[arow][8];
        } else if (p < 196) {
            int a1 = p / 14, a2 = p - a1 * 14;
            float dx = xi2[ag][a1 * 3 + 0] - xjs[arow][a2 * 3 + 0];
            float dy = xi2[ag][a1 * 3 + 1] - xjs[arow][a2 * 3 + 1];
            float dz = xi2[ag][a1 * 3 + 2] - xjs[arow][a2 * 3 + 2];
            float dd = sqrtf(dx * dx + dy * dy + dz * dz + 1e-6f);
            dd = fminf(dd, 27.f);                     // tail < 3e-14: negligible
            float coef = mi2[ag][a1] * mjs[arow][a2];
            float w = __expf(1.70666667f * dd);       // exp(2*u*dv), u = 0.8*dd
            float e[16];
            #pragma unroll
            for (int rs = 0; rs < 16; rs += 4) {      // 4 chains of 4: no underflow bridge
                float tt = (dd - (float)rs * 1.33333333f) * 0.8f;
                e[rs]     = __expf(-tt * tt) * coef;
                e[rs + 1] = e[rs]     * w * cj[rs + 1];
                e[rs + 2] = e[rs + 1] * w * cj[rs + 2];
                e[rs + 3] = e[rs + 2] * w * cj[rs + 3];
            }
            union { ushort u[16]; uint4 v[2]; } o;
            #pragma unroll
            for (int j = 0; j < 16; ++j) o.u[j] = f2bf(e[j]);
            *(uint4*)&As[arow][apl * 16]     = o.v[0];
            *(uint4*)&As[arow][apl * 16 + 8] = o.v[1];
        } else {                                      // pad cols (last chunk)
            uint4 z = {0u, 0u, 0u, 0u};
            *(uint4*)&As[arow][apl * 16]     = z;
            *(uint4*)&As[arow][apl * 16 + 8] = z;
        }
        __syncthreads();    // drains vmcnt (Bs) + lgkm (As)

        // 3. MFMA: 2 K-steps of 32
        #pragma unroll
        for (int ks = 0; ks < 2; ++ks) {
            const int ko = ks * 32 + lk * 8;
            const int sw = (((ks << 2) | lk) ^ (l16 & 7)) * 8;  // de-swizzle
            bf16x8 a0 = *(const bf16x8*)&As[mh * 32 + l16][ko];
            bf16x8 a1 = *(const bf16x8*)&As[mh * 32 + 16 + l16][ko];
            bf16x8 b0 = *(const bf16x8*)&Bs[(nh * 64 + l16) * 64 + sw];
            bf16x8 b1 = *(const bf16x8*)&Bs[(nh * 64 + 16 + l16) * 64 + sw];
            bf16x8 b2 = *(const bf16x8*)&Bs[(nh * 64 + 32 + l16) * 64 + sw];
            bf16x8 b3 = *(const bf16x8*)&Bs[(nh * 64 + 48 + l16) * 64 + sw];
            acc[0][0] = __builtin_amdgcn_mfma_f32_16x16x32_bf16(a0, b0, acc[0][0], 0, 0, 0);
            acc[0][1] = __builtin_amdgcn_mfma_f32_16x16x32_bf16(a0, b1, acc[0][1], 0, 0, 0);
            acc[0][2] = __builtin_amdgcn_mfma_f32_16x16x32_bf16(a0, b2, acc[0][2], 0, 0, 0);
            acc[0][3] = __builtin_amdgcn_mfma_f32_16x16x32_bf16(a0, b3, acc[0][3], 0, 0, 0);
            acc[1][0] = __builtin_amdgcn_mfma_f32_16x16x32_bf16(a1, b0, acc[1][0], 0, 0, 0);
            acc[1][1] = __builtin_amdgcn_mfma_f32_16x16x32_bf16(a1, b1, acc[1][1], 0, 0, 0);
            acc[1][2] = __builtin_amdgcn_mfma_f32_16x16x32_bf16(a1, b2, acc[1][2], 0, 0, 0);
            acc[1][3] = __builtin_amdgcn_mfma_f32_16x16x32_bf16(a1, b3, acc[1][3], 0, 0, 0);
        }
        __syncthreads();
    }

    // ---- LayerNorm epilogue ----
    // C/D layout: col = lane&15, row_in_frag = (lane>>4)*4 + reg  [m89]
    #pragma unroll
    for (int f = 0; f < 2; ++f) {
        #pragma unroll
        for (int reg = 0; reg < 4; ++reg) {
            float s = acc[f][0][reg] + acc[f][1][reg] + acc[f][2][reg] + acc[f][3][reg];
            float q = acc[f][0][reg] * acc[f][0][reg] + acc[f][1][reg] * acc[f][1][reg]
                    + acc[f][2][reg] * acc[f][2][reg] + acc[f][3][reg] * acc[f][3][reg];
            #pragma unroll
            for (int m = 1; m < 16; m <<= 1) {
                s += __shfl_xor(s, m);
                q += __shfl_xor(q, m);
            }
            if (l16 == 0) {
                int row = mh * 32 + f * 16 + lk * 4 + reg;
                lnS[row][nh] = s;
                lnQ[row][nh] = q;
            }
        }
    }
    __syncthreads();

    float gl[4], bl[4];
    #pragma unroll
    for (int nf = 0; nf < 4; ++nf) {
        int col = nh * 64 + nf * 16 + l16;
        gl[nf] = gamma[col];
        bl[nf] = beta[col];
    }
    #pragma unroll
    for (int f = 0; f < 2; ++f) {
        #pragma unroll
        for (int reg = 0; reg < 4; ++reg) {
            int r = mh * 32 + f * 16 + lk * 4 + reg;
            int e = r & 31, g = r >> 5;
            if (e < TOPK) {
                float s = lnS[r][0] + lnS[r][1];
                float q = lnQ[r][0] + lnQ[r][1];
                float mean = s * (1.f / 128.f);
                float var = q * (1.f / 128.f) - mean * mean;
                float inv = 1.f / sqrtf(var + 1e-5f);
                float* dst = &E[((size_t)((i0 + g) * TOPK + e)) * 128];
                #pragma unroll
                for (int nf = 0; nf < 4; ++nf) {
                    int col = nh * 64 + nf * 16 + l16;
                    dst[col] = (acc[f][nf][reg] - mean) * inv * gl[nf] + bl[nf];
                }
            }
        }
    }
}

// ---------------------------------------------------------------------------
extern "C" void kernel_launch(void* const* d_in, const int* in_sizes, int n_in,
                              void* d_out, int out_size, void* d_ws, size_t ws_size,
                              hipStream_t stream)
{
    const float* x       = (const float*)d_in[0];
    const float* mask    = (const float*)d_in[1];
    const float* a14m    = (const float*)d_in[2];
    const float* feat    = (const float*)d_in[3];
    const float* W_pos   = (const float*)d_in[4];
    const float* b_pos   = (const float*)d_in[5];
    const float* W_edge  = (const float*)d_in[6];
    const float* gamma_e = (const float*)d_in[7];
    const float* beta_e  = (const float*)d_in[8];
    const float* W_node  = (const float*)d_in[9];
    const float* gamma_n = (const float*)d_in[10];
    const float* beta_n  = (const float*)d_in[11];
    const int*   S       = (const int*)d_in[12];
    const int*   R_idx   = (const int*)d_in[13];
    const int*   chain   = (const int*)d_in[14];

    float* out     = (float*)d_out;
    float* V       = out;                                  // 1536*128
    float* E       = out + 196608;                         // 1536*30*128
    float* out_idx = out + 196608 + 5898240;               // 1536*30
    float* out_x   = out_idx + 46080;                      // 1536*14*3

    ushort* Wt = (ushort*)d_ws;                            // 128*3200 bf16 = 819200 B

    convert_wedge<<<dim3(KPAD / 64, 2), 256, 0, stream>>>(W_edge, Wt);
    topk_kernel<<<LL, 64, 0, stream>>>(x, mask, out_idx, out_x);
    node_kernel<<<LL, 128, 0, stream>>>(feat, W_node, gamma_n, beta_n, S, V);
    edge_mfma_kernel<<<LL / 2, 256, 0, stream>>>(x, mask, a14m, W_pos, b_pos, Wt,
                                                 gamma_e, beta_e, R_idx, chain,
                                                 out_idx, E);
}